// Round 1
// baseline (347.342 us; speedup 1.0000x reference)
//
#include <hip/hip_runtime.h>

// 4-layer GRU stack, B=4096, T=256. 256 persistent blocks x 768 threads
// (12 waves, 3 per SIMD), 16 batch rows per block (one M=16 MFMA tile).
//
// Wavefront pipelining across layers with PER-SIMD BALANCED jobs:
//   jobs = {L0 s0/s1 split by C-rows (4 half-jobs), L0 s2/s3 full,
//           L1 s0/s1, L2 s0/s1, L3 s0/s1}  -> 12 jobs, one per wave.
//   With wave->SIMD = w%4, every SIMD gets {half, full, full} = 60
//   transcendental instrs/step — exactly balanced.
//
// NEW (this round): gate phase DEFERRED ACROSS THE BARRIER (software
// pipeline, defer-by-one). Iteration s:
//   GATE(accs of iter s-1) -> write h -> barrier -> [stage x] ->
//   ds_read A-frags -> MFMA into the other acc set.
// MFMA results are consumed one full iteration later (matrix-pipe latency
// hidden behind the barrier + next gate phase); ds_reads feed MFMAs whose
// results aren't needed this iter. Buffer parity re-derived for this
// schedule: h_l(t) is written at iter t+lay+1 into buf[s&1]; ALL readers
// (own h(t-1) and below-layer h(t)) read buf[s&1] post-barrier same iter.
// Two named acc sets ping-pong via 2x loop unroll (no runtime indexing).
// Arithmetic is bit-identical to the previous kernel.

typedef __attribute__((ext_vector_type(8))) __bf16 bf16x8;
typedef __attribute__((ext_vector_type(4))) float f32x4;

#define TT 256
#define FF 20
#define BT 16
#define CH 64      // x chunk steps held in LDS
#define SH0 72     // h0 LDS row stride (bf16), padded from 64
#define SH1 40     // h1/h2/h3 LDS row stride, padded from 32
#define XSTR 648   // x_ch t-plane stride (bf16): 16*40 + 8 pad
#define NTHR 768

__device__ __forceinline__ f32x4 mfma16(bf16x8 a, bf16x8 b, f32x4 c) {
  return __builtin_amdgcn_mfma_f32_16x16x32_bf16(a, b, c, 0, 0, 0);
}

// NaN-free, clamp-free: correct limits at +-inf (rcp(inf)=0).
__device__ __forceinline__ float sigm(float x) {
  return __builtin_amdgcn_rcpf(1.f + __builtin_amdgcn_exp2f(-1.44269504f * x));
}
__device__ __forceinline__ float tanh_(float x) {
  return __builtin_amdgcn_rcpf(1.f + __builtin_amdgcn_exp2f(-2.88539008f * x)) * 2.f - 1.f;
}

// B-operand fragment from global row-major W[K][N]: lane holds col n, k=kbase+j.
__device__ __forceinline__ bf16x8 bfragW(const float* W, int Kreal, int N,
                                         int ncol, int kbase) {
  bf16x8 r;
#pragma unroll
  for (int j = 0; j < 8; ++j) {
    int k = kbase + j;
    r[j] = (__bf16)(k < Kreal ? W[k * N + ncol] : 0.f);
  }
  return r;
}

extern "C" __global__ void __launch_bounds__(NTHR, 3)
gru4(const float* __restrict__ inp, const float* __restrict__ Wemb,
     const float* __restrict__ k0, const float* __restrict__ rk0, const float* __restrict__ b0,
     const float* __restrict__ k1, const float* __restrict__ rk1, const float* __restrict__ b1,
     const float* __restrict__ k2, const float* __restrict__ rk2, const float* __restrict__ b2,
     const float* __restrict__ k3, const float* __restrict__ rk3, const float* __restrict__ b3,
     const float* __restrict__ Wd, const float* __restrict__ bd,
     float* __restrict__ out)
{
  __shared__ __align__(16) __bf16 x_ch[CH * XSTR];       // ~83 KB
  __shared__ __align__(16) __bf16 h0_lds[2][BT * SH0];
  __shared__ __align__(16) __bf16 h1_lds[2][BT * SH1];
  __shared__ __align__(16) __bf16 h2_lds[2][BT * SH1];
  __shared__ __align__(16) __bf16 h3_lds[2][BT * SH1];
  __shared__ __align__(16) float h3f[BT * 32];

  const int tid  = threadIdx.x;
  const int lane = tid & 63;
  const int w    = tid >> 6;        // wave 0..11
  const int col  = lane & 15;       // C col / B n / A m index
  const int kb   = (lane >> 4) * 8; // A/B k base within a k-tile
  const int rowq = (lane >> 4) * 4; // C row base (batch)
  const long bbase = (long)blockIdx.x * BT;
  const float* binp = inp + bbase * TT * FF;

  bf16x8 zf;
#pragma unroll
  for (int j = 0; j < 8; ++j) zf[j] = (__bf16)0.f;

  // ---- uniform per-wave job config (shared variables across all roles) ----
  bf16x8 Wz0 = zf, Wz1 = zf, Wz2 = zf;
  bf16x8 Wr0 = zf, Wr1 = zf, Wr2 = zf;
  bf16x8 Wgx0 = zf, Wgx1 = zf, Wgx2 = zf;
  bf16x8 Wgh0 = zf, Wgh1 = zf, Wgh2 = zf;
  float bz = 0.f, br = 0.f, bxh = 0.f, bhh = 0.f;
  const __bf16 *A0b = x_ch, *A1b = x_ch, *A2b = x_ch;
  int D0 = 0, D1 = 0, D2 = 0;
  __bf16* Wwr0 = (__bf16*)h3f;
  int WD = 0, wstride = SH1;
  int lay = 0;
  bool doLo = false, doHi = false, threeA = false;

  if (w < 6) {
    // L0: w0..w3 = row-halves of slices 0,1; w4,w5 = full slices 2,3.
    lay = 0; threeA = true;
    const int sl = (w < 4) ? (w >> 1) : (w - 2);
    doLo = (w >= 4) || ((w & 1) == 0);
    doHi = (w >= 4) || ((w & 1) == 1);
    const int u = sl * 16 + col;
    Wz0 = bfragW(k0, 23, 192, u, kb);
    Wz1 = bfragW(rk0, 64, 192, u, kb);
    Wz2 = bfragW(rk0, 64, 192, u, 32 + kb);
    Wr0 = bfragW(k0, 23, 192, 64 + u, kb);
    Wr1 = bfragW(rk0, 64, 192, 64 + u, kb);
    Wr2 = bfragW(rk0, 64, 192, 64 + u, 32 + kb);
    Wgx0 = bfragW(k0, 23, 192, 128 + u, kb);
    Wgh1 = bfragW(rk0, 64, 192, 128 + u, kb);
    Wgh2 = bfragW(rk0, 64, 192, 128 + u, 32 + kb);
    bz  = b0[u] + b0[192 + u];
    br  = b0[64 + u] + b0[192 + 64 + u];
    bxh = b0[128 + u];
    bhh = b0[192 + 128 + u];
    A1b = &h0_lds[0][col * SH0 + kb];      D1 = BT * SH0;
    A2b = &h0_lds[0][col * SH0 + 32 + kb]; D2 = BT * SH0;
    Wwr0 = &h0_lds[0][rowq * SH0 + sl * 16 + col];
    WD = BT * SH0; wstride = SH0;
  } else if (w < 8) {
    // L1: slices 0,1 full.
    lay = 1; threeA = true; doLo = doHi = true;
    const int u = (w - 6) * 16 + col;
    Wz0 = bfragW(k1, 64, 96, u, kb);
    Wz1 = bfragW(k1, 64, 96, u, 32 + kb);
    Wz2 = bfragW(rk1, 32, 96, u, kb);
    Wr0 = bfragW(k1, 64, 96, 32 + u, kb);
    Wr1 = bfragW(k1, 64, 96, 32 + u, 32 + kb);
    Wr2 = bfragW(rk1, 32, 96, 32 + u, kb);
    Wgx0 = bfragW(k1, 64, 96, 64 + u, kb);
    Wgx1 = bfragW(k1, 64, 96, 64 + u, 32 + kb);
    Wgh2 = bfragW(rk1, 32, 96, 64 + u, kb);
    bz  = b1[u] + b1[96 + u];
    br  = b1[32 + u] + b1[96 + 32 + u];
    bxh = b1[64 + u];
    bhh = b1[96 + 64 + u];
    A0b = &h0_lds[0][col * SH0 + kb];      D0 = BT * SH0;
    A1b = &h0_lds[0][col * SH0 + 32 + kb]; D1 = BT * SH0;
    A2b = &h1_lds[0][col * SH1 + kb];      D2 = BT * SH1;
    Wwr0 = &h1_lds[0][rowq * SH1 + (w - 6) * 16 + col];
    WD = BT * SH1; wstride = SH1;
  } else if (w < 10) {
    // L2: slices 0,1 full.
    lay = 2; threeA = false; doLo = doHi = true;
    const int u = (w - 8) * 16 + col;
    Wz0 = bfragW(k2, 32, 96, u, kb);
    Wz1 = bfragW(rk2, 32, 96, u, kb);
    Wr0 = bfragW(k2, 32, 96, 32 + u, kb);
    Wr1 = bfragW(rk2, 32, 96, 32 + u, kb);
    Wgx0 = bfragW(k2, 32, 96, 64 + u, kb);
    Wgh1 = bfragW(rk2, 32, 96, 64 + u, kb);
    bz  = b2[u] + b2[96 + u];
    br  = b2[32 + u] + b2[96 + 32 + u];
    bxh = b2[64 + u];
    bhh = b2[96 + 64 + u];
    A0b = &h1_lds[0][col * SH1 + kb]; D0 = BT * SH1;
    A1b = &h2_lds[0][col * SH1 + kb]; D1 = BT * SH1;
    A2b = A1b; D2 = D1;
    Wwr0 = &h2_lds[0][rowq * SH1 + (w - 8) * 16 + col];
    WD = BT * SH1; wstride = SH1;
  } else {
    // L3: slices 0,1 full.
    lay = 3; threeA = false; doLo = doHi = true;
    const int u = (w - 10) * 16 + col;
    Wz0 = bfragW(k3, 32, 96, u, kb);
    Wz1 = bfragW(rk3, 32, 96, u, kb);
    Wr0 = bfragW(k3, 32, 96, 32 + u, kb);
    Wr1 = bfragW(rk3, 32, 96, 32 + u, kb);
    Wgx0 = bfragW(k3, 32, 96, 64 + u, kb);
    Wgh1 = bfragW(rk3, 32, 96, 64 + u, kb);
    bz  = b3[u] + b3[96 + u];
    br  = b3[32 + u] + b3[96 + 32 + u];
    bxh = b3[64 + u];
    bhh = b3[96 + 64 + u];
    A0b = &h2_lds[0][col * SH1 + kb]; D0 = BT * SH1;
    A1b = &h3_lds[0][col * SH1 + kb]; D1 = BT * SH1;
    A2b = A1b; D2 = D1;
    Wwr0 = &h3_lds[0][rowq * SH1 + (w - 10) * 16 + col];
    WD = BT * SH1; wstride = SH1;
  }

  const __bf16* xb = &x_ch[col * 40 + kb];  // L0 x A-frag base (per t-plane)

  // ------------- zero-init h state -------------
  {
    __bf16* p0 = (__bf16*)h0_lds;
    for (int i = tid; i < 2 * BT * SH0; i += NTHR) p0[i] = (__bf16)0.f;
    __bf16* p1 = (__bf16*)h1_lds;
    __bf16* p2 = (__bf16*)h2_lds;
    __bf16* p3 = (__bf16*)h3_lds;
    for (int i = tid; i < 2 * BT * SH1; i += NTHR) {
      p1[i] = (__bf16)0.f; p2[i] = (__bf16)0.f; p3[i] = (__bf16)0.f;
    }
  }
  float hreg[4] = {0.f, 0.f, 0.f, 0.f};
  __syncthreads();

  // ---- bulk x staging every CH steps ----
  auto stageX = [&](int s) {
    for (int idx = tid; idx < BT * CH; idx += NTHR) {
      const int row = idx >> 6;          // CH = 64
      const int tq  = idx & (CH - 1);
      const float* p = binp + ((long)row * TT + s + tq) * FF;
      float4 v0 = *(const float4*)(p);
      float4 v1 = *(const float4*)(p + 4);
      float4 v2 = *(const float4*)(p + 8);
      float4 v3 = *(const float4*)(p + 12);
      float4 v4 = *(const float4*)(p + 16);
      float4 e  = *(const float4*)(Wemb + 4 * (int)v0.y);
      __bf16* d = &x_ch[tq * XSTR + row * 40];
      bf16x8 q0 = {(__bf16)v0.x, (__bf16)v0.z, (__bf16)v0.w, (__bf16)v1.x,
                   (__bf16)v1.y, (__bf16)v1.z, (__bf16)v1.w, (__bf16)v2.x};
      bf16x8 q1 = {(__bf16)v2.y, (__bf16)v2.z, (__bf16)v2.w, (__bf16)v3.x,
                   (__bf16)v3.y, (__bf16)v3.z, (__bf16)v3.w, (__bf16)v4.x};
      bf16x8 q2 = {(__bf16)v4.y, (__bf16)v4.z, (__bf16)v4.w, (__bf16)e.x,
                   (__bf16)e.y,  (__bf16)e.z,  (__bf16)e.w,  (__bf16)0.f};
      *(bf16x8*)(d)      = q0;
      *(bf16x8*)(d + 8)  = q1;
      *(bf16x8*)(d + 16) = q2;
      *(bf16x8*)(d + 24) = zf;
    }
  };

  // two named acc sets (ping-pong via 2x unroll; no runtime indexing)
  f32x4 az0 = {0.f,0.f,0.f,0.f}, ar0 = az0, axh0 = az0, ahh0 = az0;
  f32x4 az1 = az0, ar1 = az0, axh1 = az0, ahh1 = az0;

#define GATE(O, r) { \
    float z  = sigm(az##O[r]); \
    float rg = sigm(ar##O[r]); \
    float hc = tanh_(fmaf(rg, ahh##O[r], axh##O[r])); \
    float hn = fmaf(z, hreg[r] - hc, hc); \
    hreg[r] = hn; \
    wr[(r) * wstride] = (__bf16)hn; }

#define ITER(S, N, O) { \
    const int tg_ = (S) - lay - 1; \
    if (tg_ >= 0 && tg_ < TT) { \
      __bf16* wr = Wwr0 + ((S) & 1) * WD; \
      if (doLo) { GATE(O, 0) GATE(O, 1) } \
      if (doHi) { GATE(O, 2) GATE(O, 3) } \
    } \
    __syncthreads(); \
    if (((S) & (CH - 1)) == 0 && (S) < TT) { stageX(S); __syncthreads(); } \
    const int tm_ = (S) - lay; \
    if (tm_ >= 0 && tm_ < TT) { \
      const int rb_ = (S) & 1; \
      const __bf16* a0p = (lay == 0) ? (xb + ((S) & (CH - 1)) * XSTR) \
                                     : (A0b + rb_ * D0); \
      bf16x8 A0 = *(const bf16x8*)a0p; \
      bf16x8 A1 = *(const bf16x8*)(A1b + rb_ * D1); \
      az##N  = (f32x4){bz, bz, bz, bz}; \
      ar##N  = (f32x4){br, br, br, br}; \
      axh##N = (f32x4){bxh, bxh, bxh, bxh}; \
      ahh##N = (f32x4){bhh, bhh, bhh, bhh}; \
      az##N  = mfma16(A0, Wz0, az##N);   az##N  = mfma16(A1, Wz1, az##N); \
      ar##N  = mfma16(A0, Wr0, ar##N);   ar##N  = mfma16(A1, Wr1, ar##N); \
      axh##N = mfma16(A0, Wgx0, axh##N); axh##N = mfma16(A1, Wgx1, axh##N); \
      ahh##N = mfma16(A0, Wgh0, ahh##N); ahh##N = mfma16(A1, Wgh1, ahh##N); \
      if (threeA) { \
        bf16x8 A2 = *(const bf16x8*)(A2b + rb_ * D2); \
        az##N  = mfma16(A2, Wz2, az##N); \
        ar##N  = mfma16(A2, Wr2, ar##N); \
        axh##N = mfma16(A2, Wgx2, axh##N); \
        ahh##N = mfma16(A2, Wgh2, ahh##N); \
      } \
    } \
  }

  // 260 iterations: last MFMA at s=258 (L3 t=255), last gate at s=259.
  for (int s2 = 0; s2 < TT + 4; s2 += 2) {
    ITER(s2, 0, 1)
    ITER(s2 + 1, 1, 0)
  }
#undef ITER
#undef GATE

  // ------------- epilogue: logits + softmax -------------
  if (w >= 10) {
#pragma unroll
    for (int r = 0; r < 4; ++r)
      h3f[(rowq + r) * 32 + (w - 10) * 16 + col] = hreg[r];
  }
  __syncthreads();

  if (tid < BT) {
    float l0 = bd[0], l1 = bd[1];
#pragma unroll
    for (int u = 0; u < 32; ++u) {
      float h = h3f[tid * 32 + u];
      l0 = fmaf(h, Wd[2 * u], l0);
      l1 = fmaf(h, Wd[2 * u + 1], l1);
    }
    float m = fmaxf(l0, l1);
    float e0 = __builtin_amdgcn_exp2f((l0 - m) * 1.44269504f);
    float e1 = __builtin_amdgcn_exp2f((l1 - m) * 1.44269504f);
    float inv = 1.f / (e0 + e1);
    out[(bbase + tid) * 2 + 0] = e0 * inv;
    out[(bbase + tid) * 2 + 1] = e1 * inv;
  }
}

extern "C" void kernel_launch(void* const* d_in, const int* in_sizes, int n_in,
                              void* d_out, int out_size, void* d_ws, size_t ws_size,
                              hipStream_t stream) {
  const float* inp  = (const float*)d_in[0];
  const float* Wemb = (const float*)d_in[1];
  const float* k0   = (const float*)d_in[2];
  const float* rk0  = (const float*)d_in[3];
  const float* b0   = (const float*)d_in[4];
  const float* k1   = (const float*)d_in[5];
  const float* rk1  = (const float*)d_in[6];
  const float* b1   = (const float*)d_in[7];
  const float* k2   = (const float*)d_in[8];
  const float* rk2  = (const float*)d_in[9];
  const float* b2   = (const float*)d_in[10];
  const float* k3   = (const float*)d_in[11];
  const float* rk3  = (const float*)d_in[12];
  const float* b3   = (const float*)d_in[13];
  const float* Wd   = (const float*)d_in[14];
  const float* bd   = (const float*)d_in[15];
  float* out = (float*)d_out;

  const int Btot = in_sizes[0] / (TT * FF);   // 4096
  dim3 grid(Btot / BT);                       // 256 blocks
  gru4<<<grid, NTHR, 0, stream>>>(inp, Wemb, k0, rk0, b0, k1, rk1, b1,
                                  k2, rk2, b2, k3, rk3, b3, Wd, bd, out);
}